// Round 2
// baseline (621.493 us; speedup 1.0000x reference)
//
#include <hip/hip_runtime.h>

typedef unsigned short u16;
typedef unsigned int u32;
typedef _Float16 f16;
typedef f16 f16x2 __attribute__((ext_vector_type(2)));
typedef f16 f16x8 __attribute__((ext_vector_type(8)));
typedef __fp16 h16x2 __attribute__((ext_vector_type(2)));  // pkrtz return type
typedef float f32x4 __attribute__((ext_vector_type(4)));

#define M_DIM 8192
#define N_DIM 4096
#define K_DIM 4096

// ---------------------------------------------------------------------------
// Fused pre-pass (unchanged — isolate the GEMM structural change this round).
//  range 0: X fp32 -> fp16 (8 elems/thread, pkrtz)
//  range 1: repack 4-bit weights into splice-friendly nibble order
//  range 2: invmn[g][n] = { dup16(f16(1/scale)), dup16(f16(mn - 16*f16(1/scale))) }
// ---------------------------------------------------------------------------
#define XCVT_BLOCKS 16384  // M*K/8/256
#define W4_BLOCKS 8192     // N*(K/8)/256
#define IM_BLOCKS 1024     // 64*N/256

__global__ __launch_bounds__(256) void prep_kernel(
    const float4* __restrict__ x, uint4* __restrict__ xh,
    const int* __restrict__ packed, u32* __restrict__ w4,
    const float* __restrict__ mn, const float* __restrict__ scale,
    uint2* __restrict__ invmn) {
  int b = blockIdx.x;
  if (b < XCVT_BLOCKS) {
    int i = b * 256 + threadIdx.x;
    float4 a0 = x[2 * i], a1 = x[2 * i + 1];
    h16x2 h0 = __builtin_amdgcn_cvt_pkrtz(a0.x, a0.y);
    h16x2 h1 = __builtin_amdgcn_cvt_pkrtz(a0.z, a0.w);
    h16x2 h2 = __builtin_amdgcn_cvt_pkrtz(a1.x, a1.y);
    h16x2 h3 = __builtin_amdgcn_cvt_pkrtz(a1.z, a1.w);
    uint4 o;
    o.x = __builtin_bit_cast(u32, h0);
    o.y = __builtin_bit_cast(u32, h1);
    o.z = __builtin_bit_cast(u32, h2);
    o.w = __builtin_bit_cast(u32, h3);
    xh[i] = o;
  } else if (b < XCVT_BLOCKS + W4_BLOCKS) {
    int idx = (b - XCVT_BLOCKS) * 256 + threadIdx.x;  // n*512 + w
    int n = idx >> 9, w = idx & 511;
    int g = w >> 3;
    int jb = (w & 7) << 3;                      // 0..56; <32 = hi nibbles
    int sh = (jb < 32) ? 4 : 0;
    const int* p = packed + n * 2048 + g * 32 + (jb & 31);
    u32 out = 0;
#pragma unroll
    for (int t = 0; t < 8; t++) {
      u32 nib = ((u32)p[t] >> sh) & 0xFu;
      int pos = ((t & 1) ? 16 : 0) + ((t >> 1) << 2);
      out |= nib << pos;
    }
    w4[idx] = out;
  } else {
    int idx = (b - XCVT_BLOCKS - W4_BLOCKS) * 256 + threadIdx.x;  // g*4096+n
    int n = idx & 4095, g = idx >> 12;
    float sc = scale[n * 64 + g];
    float m = mn[n * 64 + g];
    f16 invh = (f16)(1.0f / sc);
    f16 mnh = (f16)(m - 16.0f * (float)invh);
    u32 ib = (u32)__builtin_bit_cast(u16, invh);
    u32 mb = (u32)__builtin_bit_cast(u16, mnh);
    uint2 o;
    o.x = ib | (ib << 16);
    o.y = mb | (mb << 16);
    invmn[idx] = o;
  }
}

// ---------------------------------------------------------------------------
// GEMM: C[M][N] = Xh[M][K](fp16) * dequant(B4)[N][K]^T + bias
// 8-phase-template port (T3+T4+T2+T5):
//  * Block 256x256, BK=64, 512 threads = 8 waves (2M x 4N), wave tile 128x64.
//  * Triple-buffered LDS (3 K-tile slots: A 32KB + B 8KB + IM 2KB = 126KB,
//    1 block/CU). Stage(t+3) issued after tile t's end barrier; steady-state
//    wait is s_waitcnt vmcnt(6) (next-next tile's 6 loads stay in flight) —
//    NEVER vmcnt(0) in the main loop (T4). 6 gload_lds/thread/tile exactly
//    (4xA16 + 1xB16 + 1xIM4); no other VMEM in the loop so counts are exact.
//  * 4 phases per K-tile, one C-quadrant each: {8x ds_read_b128 A + 4x b32 B
//    + 2x b64 IM; s_barrier; lgkmcnt(0)+sched_barrier(0) (rule #18);
//    setprio(1); dequant+16 MFMA; setprio(0)} (T3+T5).
//  * A chunk-swizzle (T2): LDS(row, c) holds global chunk c^(row&7); store
//    side via pre-swizzled GLOBAL source (gload_lds dest must stay linear),
//    read side chunk=(ks*4+lq)^(lr&7) -> 2 lanes/bank-group = free.
//  * Numerics/accumulation order identical to the verified kernel.
// ---------------------------------------------------------------------------
__device__ __forceinline__ void gload_lds16(const void* g, void* l) {
  __builtin_amdgcn_global_load_lds(
      (const __attribute__((address_space(1))) void*)g,
      (__attribute__((address_space(3))) void*)l, 16, 0, 0);
}
__device__ __forceinline__ void gload_lds4(const void* g, void* l) {
  __builtin_amdgcn_global_load_lds(
      (const __attribute__((address_space(1))) void*)g,
      (__attribute__((address_space(3))) void*)l, 4, 0, 0);
}

__global__ __launch_bounds__(512, 2) void gemm4_kernel(
    const u16* __restrict__ A,     // fp16 [8192][4096]
    const u32* __restrict__ B4,    // [4096][512] splice-ordered nibble dwords
    const uint2* __restrict__ IM,  // [64][4096] {inv2, mn2}
    const float* __restrict__ bias, float* __restrict__ C) {
  __shared__ alignas(16) u16 As[3][256 * 64];  // 3 x 32 KB, chunk-swizzled
  __shared__ alignas(16) u32 Bs[3][256 * 8];   // 3 x 8 KB raw nibble dwords
  __shared__ alignas(16) uint2 Is[3][256];     // 3 x 2 KB {inv2, mn2} per n

  const int tid = threadIdx.x;
  const int wave = tid >> 6, lane = tid & 63;
  const int lr = lane & 15, lq = lane >> 4;
  const int bn = blockIdx.x & 15, bm = blockIdx.x >> 4;
  const int m0 = bm << 8, n0 = bn << 8;
  const int wm = (wave & 1) << 7, wn = (wave >> 1) << 6;

  // ---- staging address bases (6 loads / thread / K-tile) ----
  // A: pass p covers rows p*64..+63; thread -> row p*64+(tid>>3), 16B chunk
  //    (tid&7); SOURCE chunk = (tid&7) ^ (row&7) so linear LDS dest ends up
  //    swizzled.  LDS dst = slot + p*8192 + tid*16 (linear in lane).
  const int cgA = (tid & 7) ^ ((tid >> 3) & 7);
  const u16* pA = A + (size_t)(m0 + (tid >> 3)) * K_DIM + (cgA << 3);
  // B: thread -> row (tid>>1), dwords (tid&1)*4..+3 of the tile's 8.
  const u32* pB = B4 + (size_t)(n0 + (tid >> 1)) * 512 + ((tid & 1) << 2);
  // IM: thread -> dword (n_loc = tid>>1, field = tid&1); tile t adds t*8192.
  const u32* pIg = (const u32*)IM + (size_t)(n0 + (tid >> 1)) * 2 + (tid & 1);

#define STAGE(tt, ss)                                                       \
  do {                                                                      \
    char* dA_ = (char*)(&As[(ss)][0]) + (tid << 4);                         \
    char* dB_ = (char*)(&Bs[(ss)][0]) + (tid << 4);                         \
    char* dI_ = (char*)(&Is[(ss)][0]) + (tid << 2);                         \
    _Pragma("unroll") for (int p_ = 0; p_ < 4; p_++)                        \
        gload_lds16(pA + (tt) * 64 + (size_t)p_ * 64 * K_DIM,               \
                    dA_ + p_ * 8192);                                       \
    gload_lds16(pB + (tt) * 8, dB_);                                        \
    gload_lds4(pIg + (size_t)(tt) * 8192, dI_);                             \
  } while (0)

  f32x4 acc[8][4] = {};

  // ---- prologue: fill the 3-deep pipeline, wait tile 0 only ----
  STAGE(0, 0);
  STAGE(1, 1);
  STAGE(2, 2);
  asm volatile("s_waitcnt vmcnt(12)" ::: "memory");  // tile 0 landed
  __builtin_amdgcn_s_barrier();

  int cur = 0;

#define PHASE(mh, nh)                                                         \
  do {                                                                        \
    f16x8 af[4][2];                                                           \
    _Pragma("unroll") for (int ii = 0; ii < 4; ii++)                          \
        _Pragma("unroll") for (int ks = 0; ks < 2; ks++) {                    \
      int row_ = wm + ((mh)*4 + ii) * 16 + lr;                                \
      int ch_ = ((ks << 2) + lq) ^ (lr & 7);                                  \
      af[ii][ks] = *(const f16x8*)((const char*)(&As[cur][0]) + row_ * 128 +  \
                                   (ch_ << 4));                               \
    }                                                                         \
    u32 braw[2][2];                                                           \
    uint2 imv[2];                                                             \
    _Pragma("unroll") for (int jj = 0; jj < 2; jj++) {                        \
      int rowb_ = wn + ((nh)*2 + jj) * 16 + lr;                               \
      imv[jj] = Is[cur][rowb_];                                               \
      _Pragma("unroll") for (int ks = 0; ks < 2; ks++)                        \
          braw[jj][ks] = Bs[cur][rowb_ * 8 + (ks << 2) + lq];                 \
    }                                                                         \
    __builtin_amdgcn_s_barrier();                                             \
    asm volatile("s_waitcnt lgkmcnt(0)" ::: "memory");                        \
    __builtin_amdgcn_sched_barrier(0);                                        \
    __builtin_amdgcn_s_setprio(1);                                            \
    f16x8 bf[2][2];                                                           \
    _Pragma("unroll") for (int jj = 0; jj < 2; jj++) {                        \
      f16x2 inv2 = __builtin_bit_cast(f16x2, imv[jj].x);                      \
      f16x2 mn2 = __builtin_bit_cast(f16x2, imv[jj].y);                       \
      _Pragma("unroll") for (int ks = 0; ks < 2; ks++) {                      \
        u32 d_ = braw[jj][ks];                                                \
        u32 q0 = ((d_ << 6) & 0x03C003C0u) | 0x4C004C00u;                     \
        u32 q1 = ((d_ << 2) & 0x03C003C0u) | 0x4C004C00u;                     \
        u32 q2 = ((d_ >> 2) & 0x03C003C0u) | 0x4C004C00u;                     \
        u32 q3 = ((d_ >> 6) & 0x03C003C0u) | 0x4C004C00u;                     \
        f16x2 w0 =                                                            \
            __builtin_elementwise_fma(__builtin_bit_cast(f16x2, q0), inv2, mn2); \
        f16x2 w1 =                                                            \
            __builtin_elementwise_fma(__builtin_bit_cast(f16x2, q1), inv2, mn2); \
        f16x2 w2 =                                                            \
            __builtin_elementwise_fma(__builtin_bit_cast(f16x2, q2), inv2, mn2); \
        f16x2 w3 =                                                            \
            __builtin_elementwise_fma(__builtin_bit_cast(f16x2, q3), inv2, mn2); \
        union {                                                               \
          f16x8 v;                                                            \
          u32 d[4];                                                           \
        } u_;                                                                 \
        u_.d[0] = __builtin_bit_cast(u32, w0);                                \
        u_.d[1] = __builtin_bit_cast(u32, w1);                                \
        u_.d[2] = __builtin_bit_cast(u32, w2);                                \
        u_.d[3] = __builtin_bit_cast(u32, w3);                                \
        bf[jj][ks] = u_.v;                                                    \
      }                                                                       \
    }                                                                         \
    _Pragma("unroll") for (int ii = 0; ii < 4; ii++)                          \
        _Pragma("unroll") for (int jj = 0; jj < 2; jj++)                      \
            _Pragma("unroll") for (int ks = 0; ks < 2; ks++)                  \
        acc[(mh)*4 + ii][(nh)*2 + jj] =                                       \
            __builtin_amdgcn_mfma_f32_16x16x32_f16(                           \
                af[ii][ks], bf[jj][ks], acc[(mh)*4 + ii][(nh)*2 + jj], 0, 0,  \
                0);                                                           \
    __builtin_amdgcn_s_setprio(0);                                            \
  } while (0)

#pragma unroll 1
  for (int t = 0; t < 64; ++t) {
    PHASE(0, 0);
    PHASE(1, 0);
    PHASE(0, 1);
    PHASE(1, 1);
    // tile boundary: counted wait (T4). Outstanding here = tiles {t+1, t+2}
    // (12); vmcnt(6) -> tile t+1 complete, t+2 stays in flight. Tail: t>=62
    // has <2 tiles left -> full drain is free there.
    if (t < 62)
      asm volatile("s_waitcnt vmcnt(6)" ::: "memory");
    else
      asm volatile("s_waitcnt vmcnt(0)" ::: "memory");
    __builtin_amdgcn_s_barrier();  // all waves' waits done + done reading cur
    if (t < 61) STAGE(t + 3, cur);  // (t+3)%3 == cur: slot just freed
    cur = (cur == 2) ? 0 : cur + 1;
  }
#undef PHASE
#undef STAGE

  // Epilogue: C/D layout col=lane&15, row=(lane>>4)*4+t (unchanged, verified)
#pragma unroll
  for (int j = 0; j < 4; j++) {
    int n = n0 + wn + j * 16 + lr;
    float bv = bias[n];
#pragma unroll
    for (int i = 0; i < 8; i++) {
      int mb = m0 + wm + i * 16 + (lq << 2);
#pragma unroll
      for (int t = 0; t < 4; t++)
        C[(size_t)(mb + t) * N_DIM + n] = acc[i][j][t] + bv;
    }
  }
}

// ---------------- fallback (only if ws too small): naive tiled fp32 --------
__global__ __launch_bounds__(256) void fallback_gemm(
    const float* __restrict__ x, const int* __restrict__ packed,
    const float* __restrict__ mn, const float* __restrict__ scale,
    const float* __restrict__ bias, float* __restrict__ out) {
  __shared__ float As[16][17];
  __shared__ float Bs[16][17];
  int tx = threadIdx.x & 15, ty = threadIdx.x >> 4;
  int m = blockIdx.y * 16 + ty;
  int n = blockIdx.x * 16 + tx;
  float acc = 0.f;
  for (int k0 = 0; k0 < K_DIM; k0 += 16) {
    As[ty][tx] = x[(size_t)m * K_DIM + k0 + tx];
    int nn = blockIdx.x * 16 + ty;
    int k = k0 + tx;
    int g = k >> 6, pos = k & 63;
    int p = packed[nn * 2048 + g * 32 + (pos & 31)];
    int v = (pos < 32) ? ((p >> 4) & 0xF) : (p & 0xF);
    Bs[ty][tx] = (float)v / scale[nn * 64 + g] + mn[nn * 64 + g];
    __syncthreads();
#pragma unroll
    for (int kk = 0; kk < 16; kk++) acc += As[ty][kk] * Bs[tx][kk];
    __syncthreads();
  }
  out[(size_t)m * N_DIM + n] = acc + bias[n];
}

extern "C" void kernel_launch(void* const* d_in, const int* in_sizes, int n_in,
                              void* d_out, int out_size, void* d_ws,
                              size_t ws_size, hipStream_t stream) {
  const float* x = (const float*)d_in[0];      // [4,2048,4096] fp32
  const int* packed = (const int*)d_in[1];     // [4096,64,32] int32
  const float* mn = (const float*)d_in[2];     // [4096,64,1]
  const float* scale = (const float*)d_in[3];  // [4096,64,1]
  const float* bias = (const float*)d_in[4];   // [4096]
  float* out = (float*)d_out;                  // [8192,4096]

  const size_t offW4 = (size_t)M_DIM * K_DIM * 2;          // Xh: 64 MB
  const size_t offIM = offW4 + (size_t)N_DIM * K_DIM / 2;  // W4: 8 MB
  const size_t need = offIM + (size_t)64 * N_DIM * 8;      // IM: 2 MB

  if (ws_size >= need) {
    u16* Xh = (u16*)d_ws;
    u32* W4 = (u32*)((char*)d_ws + offW4);
    uint2* IMp = (uint2*)((char*)d_ws + offIM);
    prep_kernel<<<XCVT_BLOCKS + W4_BLOCKS + IM_BLOCKS, 256, 0, stream>>>(
        (const float4*)x, (uint4*)Xh, packed, W4, mn, scale, IMp);
    gemm4_kernel<<<(M_DIM / 256) * (N_DIM / 256), 512, 0, stream>>>(
        Xh, W4, IMp, bias, out);
  } else {
    dim3 grid(N_DIM / 16, M_DIM / 16);
    fallback_gemm<<<grid, 256, 0, stream>>>(x, packed, mn, scale, bias, out);
  }
}

// Round 3
// 582.286 us; speedup vs baseline: 1.0673x; 1.0673x over previous
//
#include <hip/hip_runtime.h>

typedef unsigned short u16;
typedef unsigned int u32;
typedef _Float16 f16;
typedef f16 f16x2 __attribute__((ext_vector_type(2)));
typedef f16 f16x8 __attribute__((ext_vector_type(8)));
typedef __fp16 h16x2 __attribute__((ext_vector_type(2)));  // pkrtz return type
typedef float f32x4 __attribute__((ext_vector_type(4)));

#define M_DIM 8192
#define N_DIM 4096
#define K_DIM 4096

// ---------------------------------------------------------------------------
// Fused pre-pass. Only change this round: W4 is stored K-TILE-MAJOR
// ([64][4096][8] dwords, i.e. g*32768 + n*8 + d) so the GEMM's B staging is a
// fully coalesced contiguous block per K-tile.
// ---------------------------------------------------------------------------
#define XCVT_BLOCKS 16384  // M*K/8/256
#define W4_BLOCKS 8192     // N*(K/8)/256
#define IM_BLOCKS 1024     // 64*N/256

__global__ __launch_bounds__(256) void prep_kernel(
    const float4* __restrict__ x, uint4* __restrict__ xh,
    const int* __restrict__ packed, u32* __restrict__ w4,
    const float* __restrict__ mn, const float* __restrict__ scale,
    uint2* __restrict__ invmn) {
  int b = blockIdx.x;
  if (b < XCVT_BLOCKS) {
    int i = b * 256 + threadIdx.x;
    float4 a0 = x[2 * i], a1 = x[2 * i + 1];
    h16x2 h0 = __builtin_amdgcn_cvt_pkrtz(a0.x, a0.y);
    h16x2 h1 = __builtin_amdgcn_cvt_pkrtz(a0.z, a0.w);
    h16x2 h2 = __builtin_amdgcn_cvt_pkrtz(a1.x, a1.y);
    h16x2 h3 = __builtin_amdgcn_cvt_pkrtz(a1.z, a1.w);
    uint4 o;
    o.x = __builtin_bit_cast(u32, h0);
    o.y = __builtin_bit_cast(u32, h1);
    o.z = __builtin_bit_cast(u32, h2);
    o.w = __builtin_bit_cast(u32, h3);
    xh[i] = o;
  } else if (b < XCVT_BLOCKS + W4_BLOCKS) {
    int idx = (b - XCVT_BLOCKS) * 256 + threadIdx.x;  // n*512 + w
    int n = idx >> 9, w = idx & 511;
    int g = w >> 3;
    int jb = (w & 7) << 3;                      // 0..56; <32 = hi nibbles
    int sh = (jb < 32) ? 4 : 0;
    const int* p = packed + n * 2048 + g * 32 + (jb & 31);
    u32 out = 0;
#pragma unroll
    for (int t = 0; t < 8; t++) {
      u32 nib = ((u32)p[t] >> sh) & 0xFu;
      int pos = ((t & 1) ? 16 : 0) + ((t >> 1) << 2);
      out |= nib << pos;
    }
    // K-tile-major store: [g][n][d]
    w4[g * 32768 + n * 8 + (w & 7)] = out;
  } else {
    int idx = (b - XCVT_BLOCKS - W4_BLOCKS) * 256 + threadIdx.x;  // g*4096+n
    int n = idx & 4095, g = idx >> 12;
    float sc = scale[n * 64 + g];
    float m = mn[n * 64 + g];
    f16 invh = (f16)(1.0f / sc);
    f16 mnh = (f16)(m - 16.0f * (float)invh);
    u32 ib = (u32)__builtin_bit_cast(u16, invh);
    u32 mb = (u32)__builtin_bit_cast(u16, mnh);
    uint2 o;
    o.x = ib | (ib << 16);
    o.y = mb | (mb << 16);
    invmn[idx] = o;
  }
}

// ---------------------------------------------------------------------------
// GEMM: C[M][N] = Xh[M][K](fp16) * dequant(B4)[N][K]^T + bias
// Round-3 structure (fixes round-2's duplicated work):
//  * 256x256 tile, 8 waves (2M x 4N), wave tile 128x64, BK=64.
//  * 3-slot LDS pipeline, 6 gload_lds/thread/tile, counted vmcnt(6) at tile
//    boundary (T4) — loads span barriers, never drained mid-loop.
//  * Per tile: B nibbles (16 b32) + IM (4 b64) read ONCE into registers,
//    dequanted ONCE -> bf[4][2] (held across tile). Two MFMA phases (mh=0/1):
//    {8x A ds_read_b128; s_barrier; lgkmcnt(0)+sched_barrier(0); setprio(1);
//     [dequant in P0] + 32 MFMA; setprio(0)}.
//    -> per tile/wave: 16 b128 + 16 b32 + 4 b64 LDS reads, 64 MFMA, 1x dequant.
//  * A chunk-swizzle (store-side via pre-swizzled global source; read chunk
//    (ks*4+lq)^(lr&7)) -> 2 lanes/bank. B LDS ks-major [2][256][4]: bank =
//    4*(lr&7)+lq -> 2 lanes/bank. Is [256] uint2: 4 dwords/bank over 4-cyc
//    min -> conflict-free. All LDS reads conflict-free.
//  * XCD-chunked block swizzle (bijective: 512 % 8 == 0): XCD x owns bm in
//    [4x,4x+4) -> A panels stay in the XCD's L2, cutting FETCH + vmcnt waits.
//  * Numerics / accumulation order identical to the verified round-0 kernel.
// ---------------------------------------------------------------------------
__device__ __forceinline__ void gload_lds16(const void* g, void* l) {
  __builtin_amdgcn_global_load_lds(
      (const __attribute__((address_space(1))) void*)g,
      (__attribute__((address_space(3))) void*)l, 16, 0, 0);
}
__device__ __forceinline__ void gload_lds4(const void* g, void* l) {
  __builtin_amdgcn_global_load_lds(
      (const __attribute__((address_space(1))) void*)g,
      (__attribute__((address_space(3))) void*)l, 4, 0, 0);
}

__global__ __launch_bounds__(512, 2) void gemm4_kernel(
    const u16* __restrict__ A,     // fp16 [8192][4096]
    const u32* __restrict__ B4,    // [64][4096][8] K-tile-major nibble dwords
    const uint2* __restrict__ IM,  // [64][4096] {inv2, mn2}
    const float* __restrict__ bias, float* __restrict__ C) {
  __shared__ alignas(16) u16 As[3][256 * 64];   // 3 x 32 KB, chunk-swizzled
  __shared__ alignas(16) u32 Bs[3][2][256][4];  // 3 x 8 KB, ks-major
  __shared__ alignas(16) uint2 Is[3][256];      // 3 x 2 KB {inv2, mn2}

  const int tid = threadIdx.x;
  const int wave = tid >> 6, lane = tid & 63;
  const int lr = lane & 15, lq = lane >> 4;
  // XCD-chunked swizzle: 512 wgs round-robin to 8 XCDs; remap so XCD x gets
  // contiguous wg [64x, 64x+64) => bm in [4x, 4x+4).
  const int wg = ((int)blockIdx.x & 7) * 64 + ((int)blockIdx.x >> 3);
  const int bn = wg & 15, bm = wg >> 4;
  const int m0 = bm << 8, n0 = bn << 8;
  const int wm = (wave & 1) << 7, wn = (wave >> 1) << 6;

  // ---- staging bases (6 loads / thread / K-tile) ----
  // A: pass p covers rows p*64 + (tid>>3); SOURCE chunk = (tid&7)^(row&7) so
  //    the linear LDS dest ends up chunk-swizzled.
  const int cgA = (tid & 7) ^ ((tid >> 3) & 7);
  const u16* pA = A + (size_t)(m0 + (tid >> 3)) * K_DIM + (cgA << 3);
  // B: thread -> ks = tid>>8, n = tid&255, dwords ks*4..+3 (coalesced 2KB/wave)
  const u32* pB = B4 + (size_t)(n0 + (tid & 255)) * 8 + ((tid >> 8) << 2);
  // IM: thread -> dword (n = tid>>1, field = tid&1)
  const u32* pIg = (const u32*)IM + (size_t)(n0 + (tid >> 1)) * 2 + (tid & 1);

#define STAGE(tt, ss)                                                     \
  do {                                                                    \
    char* dA_ = (char*)(&As[(ss)][0]) + (tid << 4);                       \
    char* dB_ = (char*)(&Bs[(ss)][0][0][0]) + (tid << 4);                 \
    char* dI_ = (char*)(&Is[(ss)][0]) + (tid << 2);                       \
    _Pragma("unroll") for (int p_ = 0; p_ < 4; p_++)                      \
        gload_lds16(pA + (tt) * 64 + (size_t)p_ * 64 * K_DIM,             \
                    dA_ + p_ * 8192);                                     \
    gload_lds16(pB + (size_t)(tt) * 32768, dB_);                          \
    gload_lds4(pIg + (size_t)(tt) * 8192, dI_);                           \
  } while (0)

  f32x4 acc[8][4] = {};

  // ---- prologue: fill 3-deep pipeline; wait tile 0 only ----
  STAGE(0, 0);
  STAGE(1, 1);
  STAGE(2, 2);
  asm volatile("s_waitcnt vmcnt(12)" ::: "memory");  // tile 0 landed
  __builtin_amdgcn_s_barrier();

  int cur = 0;

#pragma unroll 1
  for (int t = 0; t < 64; ++t) {
    const char* aB = (const char*)(&As[cur][0]);

    // ---- P0 issue: all B + IM + A(mh=0) reads ----
    uint2 isv[4];
    u32 braw[4][2];
    f16x8 af[4][2];
#pragma unroll
    for (int j = 0; j < 4; j++) {
      int rowb = wn + j * 16 + lr;
      isv[j] = Is[cur][rowb];
#pragma unroll
      for (int ks = 0; ks < 2; ks++) braw[j][ks] = Bs[cur][ks][rowb][lq];
    }
#pragma unroll
    for (int ii = 0; ii < 4; ii++)
#pragma unroll
      for (int ks = 0; ks < 2; ks++) {
        int row_ = wm + ii * 16 + lr;
        int ch_ = ((ks << 2) + lq) ^ (lr & 7);
        af[ii][ks] = *(const f16x8*)(aB + row_ * 128 + (ch_ << 4));
      }
    __builtin_amdgcn_s_barrier();
    asm volatile("s_waitcnt lgkmcnt(0)" ::: "memory");
    __builtin_amdgcn_sched_barrier(0);
    __builtin_amdgcn_s_setprio(1);
    // dequant ONCE per tile -> bf[4][2], held through P1
    f16x8 bf[4][2];
#pragma unroll
    for (int j = 0; j < 4; j++) {
      f16x2 inv2 = __builtin_bit_cast(f16x2, isv[j].x);
      f16x2 mn2 = __builtin_bit_cast(f16x2, isv[j].y);
#pragma unroll
      for (int ks = 0; ks < 2; ks++) {
        u32 d_ = braw[j][ks];
        u32 q0 = ((d_ << 6) & 0x03C003C0u) | 0x4C004C00u;  // fp16(16+v) pairs
        u32 q1 = ((d_ << 2) & 0x03C003C0u) | 0x4C004C00u;
        u32 q2 = ((d_ >> 2) & 0x03C003C0u) | 0x4C004C00u;
        u32 q3 = ((d_ >> 6) & 0x03C003C0u) | 0x4C004C00u;
        f16x2 w0 =
            __builtin_elementwise_fma(__builtin_bit_cast(f16x2, q0), inv2, mn2);
        f16x2 w1 =
            __builtin_elementwise_fma(__builtin_bit_cast(f16x2, q1), inv2, mn2);
        f16x2 w2 =
            __builtin_elementwise_fma(__builtin_bit_cast(f16x2, q2), inv2, mn2);
        f16x2 w3 =
            __builtin_elementwise_fma(__builtin_bit_cast(f16x2, q3), inv2, mn2);
        union {
          f16x8 v;
          u32 d[4];
        } u_;
        u_.d[0] = __builtin_bit_cast(u32, w0);
        u_.d[1] = __builtin_bit_cast(u32, w1);
        u_.d[2] = __builtin_bit_cast(u32, w2);
        u_.d[3] = __builtin_bit_cast(u32, w3);
        bf[j][ks] = u_.v;
      }
    }
#pragma unroll
    for (int ii = 0; ii < 4; ii++)
#pragma unroll
      for (int j = 0; j < 4; j++)
#pragma unroll
        for (int ks = 0; ks < 2; ks++)
          acc[ii][j] = __builtin_amdgcn_mfma_f32_16x16x32_f16(
              af[ii][ks], bf[j][ks], acc[ii][j], 0, 0, 0);
    __builtin_amdgcn_s_setprio(0);

    // ---- P1 issue: A(mh=1) reads ----
    f16x8 ag[4][2];
#pragma unroll
    for (int ii = 0; ii < 4; ii++)
#pragma unroll
      for (int ks = 0; ks < 2; ks++) {
        int row_ = wm + 64 + ii * 16 + lr;
        int ch_ = ((ks << 2) + lq) ^ (lr & 7);
        ag[ii][ks] = *(const f16x8*)(aB + row_ * 128 + (ch_ << 4));
      }
    __builtin_amdgcn_s_barrier();
    asm volatile("s_waitcnt lgkmcnt(0)" ::: "memory");
    __builtin_amdgcn_sched_barrier(0);
    __builtin_amdgcn_s_setprio(1);
#pragma unroll
    for (int ii = 0; ii < 4; ii++)
#pragma unroll
      for (int j = 0; j < 4; j++)
#pragma unroll
        for (int ks = 0; ks < 2; ks++)
          acc[4 + ii][j] = __builtin_amdgcn_mfma_f32_16x16x32_f16(
              ag[ii][ks], bf[j][ks], acc[4 + ii][j], 0, 0, 0);
    __builtin_amdgcn_s_setprio(0);

    // ---- tile boundary: counted wait (T4), stage t+3 into freed slot ----
    // Outstanding = tiles {t+1, t+2} (12 loads); vmcnt(6) -> t+1 complete,
    // t+2 stays in flight. Tail drains.
    if (t < 62)
      asm volatile("s_waitcnt vmcnt(6)" ::: "memory");
    else
      asm volatile("s_waitcnt vmcnt(0)" ::: "memory");
    __builtin_amdgcn_s_barrier();  // all waves synced; slot cur reusable
    if (t < 61) STAGE(t + 3, cur);
    cur = (cur == 2) ? 0 : cur + 1;
  }
#undef STAGE

  // Epilogue: C/D layout col=lane&15, row=(lane>>4)*4+t (unchanged, verified)
#pragma unroll
  for (int j = 0; j < 4; j++) {
    int n = n0 + wn + j * 16 + lr;
    float bv = bias[n];
#pragma unroll
    for (int i = 0; i < 8; i++) {
      int mb = m0 + wm + i * 16 + (lq << 2);
#pragma unroll
      for (int t = 0; t < 4; t++)
        C[(size_t)(mb + t) * N_DIM + n] = acc[i][j][t] + bv;
    }
  }
}

// ---------------- fallback (only if ws too small): naive tiled fp32 --------
__global__ __launch_bounds__(256) void fallback_gemm(
    const float* __restrict__ x, const int* __restrict__ packed,
    const float* __restrict__ mn, const float* __restrict__ scale,
    const float* __restrict__ bias, float* __restrict__ out) {
  __shared__ float As[16][17];
  __shared__ float Bs[16][17];
  int tx = threadIdx.x & 15, ty = threadIdx.x >> 4;
  int m = blockIdx.y * 16 + ty;
  int n = blockIdx.x * 16 + tx;
  float acc = 0.f;
  for (int k0 = 0; k0 < K_DIM; k0 += 16) {
    As[ty][tx] = x[(size_t)m * K_DIM + k0 + tx];
    int nn = blockIdx.x * 16 + ty;
    int k = k0 + tx;
    int g = k >> 6, pos = k & 63;
    int p = packed[nn * 2048 + g * 32 + (pos & 31)];
    int v = (pos < 32) ? ((p >> 4) & 0xF) : (p & 0xF);
    Bs[ty][tx] = (float)v / scale[nn * 64 + g] + mn[nn * 64 + g];
    __syncthreads();
#pragma unroll
    for (int kk = 0; kk < 16; kk++) acc += As[ty][kk] * Bs[tx][kk];
    __syncthreads();
  }
  out[(size_t)m * N_DIM + n] = acc + bias[n];
}

extern "C" void kernel_launch(void* const* d_in, const int* in_sizes, int n_in,
                              void* d_out, int out_size, void* d_ws,
                              size_t ws_size, hipStream_t stream) {
  const float* x = (const float*)d_in[0];      // [4,2048,4096] fp32
  const int* packed = (const int*)d_in[1];     // [4096,64,32] int32
  const float* mn = (const float*)d_in[2];     // [4096,64,1]
  const float* scale = (const float*)d_in[3];  // [4096,64,1]
  const float* bias = (const float*)d_in[4];   // [4096]
  float* out = (float*)d_out;                  // [8192,4096]

  const size_t offW4 = (size_t)M_DIM * K_DIM * 2;          // Xh: 64 MB
  const size_t offIM = offW4 + (size_t)N_DIM * K_DIM / 2;  // W4: 8 MB
  const size_t need = offIM + (size_t)64 * N_DIM * 8;      // IM: 2 MB

  if (ws_size >= need) {
    u16* Xh = (u16*)d_ws;
    u32* W4 = (u32*)((char*)d_ws + offW4);
    uint2* IMp = (uint2*)((char*)d_ws + offIM);
    prep_kernel<<<XCVT_BLOCKS + W4_BLOCKS + IM_BLOCKS, 256, 0, stream>>>(
        (const float4*)x, (uint4*)Xh, packed, W4, mn, scale, IMp);
    gemm4_kernel<<<(M_DIM / 256) * (N_DIM / 256), 512, 0, stream>>>(
        Xh, W4, IMp, bias, out);
  } else {
    dim3 grid(N_DIM / 16, M_DIM / 16);
    fallback_gemm<<<grid, 256, 0, stream>>>(x, packed, mn, scale, bias, out);
  }
}

// Round 4
// 531.824 us; speedup vs baseline: 1.1686x; 1.0949x over previous
//
#include <hip/hip_runtime.h>

typedef unsigned short u16;
typedef unsigned int u32;
typedef _Float16 f16;
typedef f16 f16x2 __attribute__((ext_vector_type(2)));
typedef f16 f16x8 __attribute__((ext_vector_type(8)));
typedef __fp16 h16x2 __attribute__((ext_vector_type(2)));  // pkrtz return type
typedef float f32x4 __attribute__((ext_vector_type(4)));

#define M_DIM 8192
#define N_DIM 4096
#define K_DIM 4096

// ---------------------------------------------------------------------------
// Fused pre-pass.
//  range 0: X fp32 -> fp16. This round: fully-coalesced form — each thread
//           loads ONE float4 (lane-contiguous) and stores ONE uint2 (8 B,
//           lane-contiguous), twice. Old form loaded x[2i],x[2i+1] = stride-32B
//           per instruction (half-utilized transactions, 2x L2 traffic).
//  range 1: repack 4-bit weights into splice-friendly nibble order
//           (n-major [4096][512], round-0 layout).
//  range 2: invmn[g][n] = { dup16(f16(1/scale)), dup16(f16(mn - 16*f16(1/scale))) }
// ---------------------------------------------------------------------------
#define XCVT_BLOCKS 16384  // M*K/8/256 (each thread: 2 float4 -> 2 uint2)
#define W4_BLOCKS 8192     // N*(K/8)/256
#define IM_BLOCKS 1024     // 64*N/256

__global__ __launch_bounds__(256) void prep_kernel(
    const float4* __restrict__ x, uint4* __restrict__ xh,
    const int* __restrict__ packed, u32* __restrict__ w4,
    const float* __restrict__ mn, const float* __restrict__ scale,
    uint2* __restrict__ invmn) {
  int b = blockIdx.x;
  if (b < XCVT_BLOCKS) {
    uint2* xh2 = (uint2*)xh;
    int i0 = b * 512 + threadIdx.x;  // float4 index == uint2 index
    float4 a0 = x[i0];
    float4 a1 = x[i0 + 256];
    h16x2 h0 = __builtin_amdgcn_cvt_pkrtz(a0.x, a0.y);
    h16x2 h1 = __builtin_amdgcn_cvt_pkrtz(a0.z, a0.w);
    h16x2 h2 = __builtin_amdgcn_cvt_pkrtz(a1.x, a1.y);
    h16x2 h3 = __builtin_amdgcn_cvt_pkrtz(a1.z, a1.w);
    uint2 o0, o1;
    o0.x = __builtin_bit_cast(u32, h0);
    o0.y = __builtin_bit_cast(u32, h1);
    o1.x = __builtin_bit_cast(u32, h2);
    o1.y = __builtin_bit_cast(u32, h3);
    xh2[i0] = o0;
    xh2[i0 + 256] = o1;
  } else if (b < XCVT_BLOCKS + W4_BLOCKS) {
    int idx = (b - XCVT_BLOCKS) * 256 + threadIdx.x;  // n*512 + w
    int n = idx >> 9, w = idx & 511;
    int g = w >> 3;
    int jb = (w & 7) << 3;                      // 0..56; <32 = hi nibbles
    int sh = (jb < 32) ? 4 : 0;
    const int* p = packed + n * 2048 + g * 32 + (jb & 31);
    u32 out = 0;
#pragma unroll
    for (int t = 0; t < 8; t++) {
      u32 nib = ((u32)p[t] >> sh) & 0xFu;
      int pos = ((t & 1) ? 16 : 0) + ((t >> 1) << 2);
      out |= nib << pos;
    }
    w4[idx] = out;
  } else {
    int idx = (b - XCVT_BLOCKS - W4_BLOCKS) * 256 + threadIdx.x;  // g*4096+n
    int n = idx & 4095, g = idx >> 12;
    float sc = scale[n * 64 + g];
    float m = mn[n * 64 + g];
    f16 invh = (f16)(1.0f / sc);
    f16 mnh = (f16)(m - 16.0f * (float)invh);
    u32 ib = (u32)__builtin_bit_cast(u16, invh);
    u32 mb = (u32)__builtin_bit_cast(u16, mnh);
    uint2 o;
    o.x = ib | (ib << 16);
    o.y = mb | (mb << 16);
    invmn[idx] = o;
  }
}

// ---------------------------------------------------------------------------
// GEMM: C[M][N] = Xh[M][K](fp16) * dequant(B4)[N][K]^T + bias
// Round-4 = round-0 structure (best measured: 292 us) + exactly two verified
// deltas:
//  (1) A chunk-swizzle (verified r1: conflicts 2.1e7 -> 4.2e6, passed check):
//      store-side via pre-swizzled GLOBAL source chunk (gload_lds dest must
//      stay linear): chunk_g = (lane&3) ^ ((lane>>3)&3) = c ^ (row_bits[2:1]);
//      read-side chunk = lq ^ ((lr>>1)&3).
//  (2) XCD-chunked bijective block swizzle (verified r3: FETCH 273->116 MB):
//      1024 wgs, 1024 % 8 == 0 -> wg = (bid&7)*128 + (bid>>3); XCD x owns
//      bm in [4x, 4x+4) -> A panels L2-resident per XCD.
// Everything else (single-buffer 2-barrier loop, 2 blocks/CU, tile geometry,
// splice dequant, epilogue) byte-identical to round 0. The r1-r3 pipelining
// attempts all regressed (m99/m100/m196 behavior: implicit wave-level overlap
// at 2 blocks/CU beats barrier-locked explicit schedules here).
// ---------------------------------------------------------------------------
__device__ __forceinline__ void gload_lds16(const void* g, void* l) {
  __builtin_amdgcn_global_load_lds(
      (const __attribute__((address_space(1))) void*)g,
      (__attribute__((address_space(3))) void*)l, 16, 0, 0);
}

__global__ __launch_bounds__(256, 2) void gemm4_kernel(
    const u16* __restrict__ A,     // fp16 [8192][4096]
    const u32* __restrict__ B4,    // [4096][512] splice-ordered nibble dwords
    const uint2* __restrict__ IM,  // [64][4096] {inv2, mn2}
    const float* __restrict__ bias, float* __restrict__ C) {
  __shared__ alignas(16) u16 As[2][256 * 32];  // [k32-subtile][row][32] 32 KB
  __shared__ alignas(16) u32 Bs[2][128 * 4];   // [k32-half][row][4 dw]  4 KB

  const int tid = threadIdx.x;
  const int wave = tid >> 6, lane = tid & 63;
  const int lr = lane & 15, lq = lane >> 4;
  // XCD-chunked bijective swizzle (1024 wgs % 8 == 0)
  const int wg = ((int)blockIdx.x & 7) * 128 + ((int)blockIdx.x >> 3);
  const int bn = wg & 31, bm = wg >> 5;
  const int m0 = bm << 8, n0 = bn << 7;
  const int wm = (wave & 1) << 7, wn = (wave >> 1) << 6;

  // A staging: wave covers rows 64*wave..+63 over 4 passes (c), 2 subtiles (s)
  // SOURCE chunk pre-swizzled: chunk_g = (lane&3) ^ (row bits [2:1]) so the
  // linear LDS dest ends up bank-swizzled.
  const int chunkg = (lane & 3) ^ ((lane >> 3) & 3);
  const u16* pA =
      A + (size_t)(m0 + (wave << 6) + (lane >> 2)) * K_DIM + (chunkg << 3);
  char* dstA = (char*)(&As[0][0]) + wave * 4096 + lane * 16;
  // B staging: 1 pass/wave: h = wave>>1, row = 64*(wave&1)+lane (dword units)
  const u32* pB = B4 + (size_t)(n0 + ((wave & 1) << 6) + lane) * 512 +
                  ((wave >> 1) << 2);
  char* dstB = (char*)(&Bs[0][0]) + wave * 1024 + lane * 16;
  const uint2* pI = IM + n0 + wn + lr;
  const int aswz = (lq ^ ((lr >> 1) & 3)) << 4;  // read-side swizzled chunk

  f32x4 acc[8][4] = {};

  for (int kk = 0; kk < 64; ++kk) {  // k0 = kk*64; group g == kk
    uint2 im[4];
    const uint2* pIt = pI + kk * 4096;
#pragma unroll
    for (int j = 0; j < 4; j++) im[j] = pIt[j * 16];

#pragma unroll
    for (int s = 0; s < 2; s++)
#pragma unroll
      for (int c = 0; c < 4; c++)
        gload_lds16(pA + kk * 64 + s * 32 + (size_t)c * 16 * K_DIM,
                    dstA + s * 16384 + c * 1024);
    gload_lds16(pB + kk * 8, dstB);
    __syncthreads();  // vmcnt(0) drain (also covers im[])

#pragma unroll
    for (int s = 0; s < 2; s++) {
      f16x8 af[8];
#pragma unroll
      for (int i = 0; i < 8; i++)
        af[i] = *(const f16x8*)((const char*)(&As[0][0]) + s * 16384 +
                                (wm + i * 16 + lr) * 64 + aswz);
      u32 braw[4];
#pragma unroll
      for (int j = 0; j < 4; j++) braw[j] = Bs[s][(wn + j * 16 + lr) * 4 + lq];

      f16x8 bf[4];
#pragma unroll
      for (int j = 0; j < 4; j++) {
        u32 d = braw[j];
        u32 q0 = ((d << 6) & 0x03C003C0u) | 0x4C004C00u;  // fp16(16+v) pairs
        u32 q1 = ((d << 2) & 0x03C003C0u) | 0x4C004C00u;
        u32 q2 = ((d >> 2) & 0x03C003C0u) | 0x4C004C00u;
        u32 q3 = ((d >> 6) & 0x03C003C0u) | 0x4C004C00u;
        f16x2 inv2 = __builtin_bit_cast(f16x2, im[j].x);
        f16x2 mn2 = __builtin_bit_cast(f16x2, im[j].y);
        f16x2 w0 = __builtin_elementwise_fma(__builtin_bit_cast(f16x2, q0), inv2, mn2);
        f16x2 w1 = __builtin_elementwise_fma(__builtin_bit_cast(f16x2, q1), inv2, mn2);
        f16x2 w2 = __builtin_elementwise_fma(__builtin_bit_cast(f16x2, q2), inv2, mn2);
        f16x2 w3 = __builtin_elementwise_fma(__builtin_bit_cast(f16x2, q3), inv2, mn2);
        union {
          f16x8 v;
          u32 d[4];
        } u;
        u.d[0] = __builtin_bit_cast(u32, w0);
        u.d[1] = __builtin_bit_cast(u32, w1);
        u.d[2] = __builtin_bit_cast(u32, w2);
        u.d[3] = __builtin_bit_cast(u32, w3);
        bf[j] = u.v;
      }
#pragma unroll
      for (int i = 0; i < 8; i++)
#pragma unroll
        for (int j = 0; j < 4; j++)
          acc[i][j] = __builtin_amdgcn_mfma_f32_16x16x32_f16(af[i], bf[j],
                                                             acc[i][j], 0, 0, 0);
    }
    __syncthreads();
  }

  // Epilogue: C/D layout col=lane&15, row=(lane>>4)*4+t (same as verified r1/r2)
#pragma unroll
  for (int j = 0; j < 4; j++) {
    int n = n0 + wn + j * 16 + lr;
    float bv = bias[n];
#pragma unroll
    for (int i = 0; i < 8; i++) {
      int mb = m0 + wm + i * 16 + (lq << 2);
#pragma unroll
      for (int t = 0; t < 4; t++)
        C[(size_t)(mb + t) * N_DIM + n] = acc[i][j][t] + bv;
    }
  }
}

// ---------------- fallback (only if ws too small): naive tiled fp32 --------
__global__ __launch_bounds__(256) void fallback_gemm(
    const float* __restrict__ x, const int* __restrict__ packed,
    const float* __restrict__ mn, const float* __restrict__ scale,
    const float* __restrict__ bias, float* __restrict__ out) {
  __shared__ float As[16][17];
  __shared__ float Bs[16][17];
  int tx = threadIdx.x & 15, ty = threadIdx.x >> 4;
  int m = blockIdx.y * 16 + ty;
  int n = blockIdx.x * 16 + tx;
  float acc = 0.f;
  for (int k0 = 0; k0 < K_DIM; k0 += 16) {
    As[ty][tx] = x[(size_t)m * K_DIM + k0 + tx];
    int nn = blockIdx.x * 16 + ty;
    int k = k0 + tx;
    int g = k >> 6, pos = k & 63;
    int p = packed[nn * 2048 + g * 32 + (pos & 31)];
    int v = (pos < 32) ? ((p >> 4) & 0xF) : (p & 0xF);
    Bs[ty][tx] = (float)v / scale[nn * 64 + g] + mn[nn * 64 + g];
    __syncthreads();
#pragma unroll
    for (int kk = 0; kk < 16; kk++) acc += As[ty][kk] * Bs[tx][kk];
    __syncthreads();
  }
  out[(size_t)m * N_DIM + n] = acc + bias[n];
}

extern "C" void kernel_launch(void* const* d_in, const int* in_sizes, int n_in,
                              void* d_out, int out_size, void* d_ws,
                              size_t ws_size, hipStream_t stream) {
  const float* x = (const float*)d_in[0];      // [4,2048,4096] fp32
  const int* packed = (const int*)d_in[1];     // [4096,64,32] int32
  const float* mn = (const float*)d_in[2];     // [4096,64,1]
  const float* scale = (const float*)d_in[3];  // [4096,64,1]
  const float* bias = (const float*)d_in[4];   // [4096]
  float* out = (float*)d_out;                  // [8192,4096]

  const size_t offW4 = (size_t)M_DIM * K_DIM * 2;          // Xh: 64 MB
  const size_t offIM = offW4 + (size_t)N_DIM * K_DIM / 2;  // W4: 8 MB
  const size_t need = offIM + (size_t)64 * N_DIM * 8;      // IM: 2 MB

  if (ws_size >= need) {
    u16* Xh = (u16*)d_ws;
    u32* W4 = (u32*)((char*)d_ws + offW4);
    uint2* IMp = (uint2*)((char*)d_ws + offIM);
    prep_kernel<<<XCVT_BLOCKS + W4_BLOCKS + IM_BLOCKS, 256, 0, stream>>>(
        (const float4*)x, (uint4*)Xh, packed, W4, mn, scale, IMp);
    gemm4_kernel<<<(M_DIM / 256) * (N_DIM / 128), 256, 0, stream>>>(
        Xh, W4, IMp, bias, out);
  } else {
    dim3 grid(N_DIM / 16, M_DIM / 16);
    fallback_gemm<<<grid, 256, 0, stream>>>(x, packed, mn, scale, bias, out);
  }
}